// Round 2
// baseline (403.615 us; speedup 1.0000x reference)
//
#include <hip/hip_runtime.h>
#include <hip/hip_bf16.h>

typedef unsigned short ushortT;
typedef __bf16 bf16x8 __attribute__((ext_vector_type(8)));
typedef float f32x4 __attribute__((ext_vector_type(4)));

#define OUT_SCALE 0.001f

// fast GELU: v * sigmoid(1.5957691*(v + 0.044715 v^3)); |err vs exact| <~1e-3
__device__ __forceinline__ float gelu_fast(float v) {
    const float u = v * fmaf(0.044715f * v, v, 1.0f);
    const float e = __expf(-1.5957691216057308f * u);
    return v * __builtin_amdgcn_rcpf(1.0f + e);
}
__device__ __forceinline__ ushortT f2bf(float f) {
    __hip_bfloat16 h = __float2bfloat16(f);
    return *reinterpret_cast<ushortT*>(&h);
}

// ---------------------------------------------------------------------------
// K2: z path. gelu(z + dwconv3x3(z) + b) written as bf16 ZB[b][v][u][c64]
// (unchanged from verified baseline)
// ---------------------------------------------------------------------------
__global__ __launch_bounds__(256) void k_gelu_z(
    const float* __restrict__ z, const float* __restrict__ wz,
    const float* __restrict__ bz, ushortT* __restrict__ zbuf)
{
    const int b   = blockIdx.x;
    const int tid = threadIdx.x;
    const int c   = tid >> 2;
    const int q   = tid & 3;

    __shared__ float   zs[64 * 260];
    __shared__ ushortT zt[16384];

    {
        const float4* src = (const float4*)(z + ((size_t)b * 64 + c) * 256 + q * 64);
        float4* dstv = (float4*)(zs + c * 260 + q * 64);
        #pragma unroll
        for (int i = 0; i < 16; ++i) dstv[i] = src[i];
    }
    __syncthreads();

    const float* wp = wz + c * 9;
    float w[9];
    #pragma unroll
    for (int i = 0; i < 9; ++i) w[i] = wp[i];
    const float bias = bz[c];
    const float* zc = zs + c * 260;

    for (int v = q * 4; v < q * 4 + 4; ++v) {
        #pragma unroll
        for (int u = 0; u < 16; ++u) {
            float acc = bias;
            #pragma unroll
            for (int dr = 0; dr < 3; ++dr) {
                const int uu = u + dr - 1;
                if (uu < 0 || uu >= 16) continue;
                #pragma unroll
                for (int dc = 0; dc < 3; ++dc) {
                    const int vv = v + dc - 1;
                    if (vv < 0 || vv >= 16) continue;
                    acc += zc[uu * 16 + vv] * w[dr * 3 + dc];
                }
            }
            const float y = acc + zc[u * 16 + v];
            zt[(v * 16 + u) * 64 + c] = f2bf(gelu_fast(y));
        }
    }
    __syncthreads();
    uint4* dst = (uint4*)(zbuf + (size_t)b * 16384);
    const uint4* s4 = (const uint4*)zt;
    for (int i = tid; i < 2048; i += 256) dst[i] = s4[i];
}

// ---------------------------------------------------------------------------
// K-fused: gelu-x + correlation in ONE kernel. grid 6144 (XCD-swizzled),
// 512 thr (8 waves). Phase A (all 512 thr): K1's gelu(x+dwconv3x3(x)+b) for
// row r, written as swizzled bf16 transpose DIRECTLY into rowbuf LDS
// [g2][T128][c32] (chunk' = chunk ^ ((T>>1)&3)) — no HBM round-trip.
// Phase B (waves 0..6): one 16-wide j-tile each, 32 MFMA(16x16x32) over K=64,
// write-once scatter to outacc. Phase C: atomicAdd the 16x97 band to out.
// ---------------------------------------------------------------------------
__global__ __launch_bounds__(512, 4) void k_fused(
    const float* __restrict__ x, const float* __restrict__ wx,
    const float* __restrict__ bx, const ushortT* __restrict__ zbuf,
    float* __restrict__ out)
{
    // bijective XCD swizzle: 6144 blocks, 8 XCDs, 768 per XCD; same-b
    // adjacent-r blocks land on the same XCD (x-row L2 reuse, atomic locality)
    const int lin = blockIdx.x;
    const int sw  = ((lin & 7) * 768) + (lin >> 3);
    const int r   = sw % 96;
    const int b   = sw / 96;
    const int tid = threadIdx.x;

    __shared__ ushortT rowbuf[8192];      // [g2][T128][c32 swizzled], 16 KB
    __shared__ float   outacc[16 * 113];  // write-once scatter target

    // zero-pad rows T in [0,8) and [104,128) of both groups: 2048 elems
    if (tid < 256) {
        const int g = tid >> 7, i = tid & 127;
        const int off = (i < 32) ? i * 8 : 3328 + (i - 32) * 8;
        *(uint4*)(&rowbuf[g * 4096 + off]) = make_uint4(0, 0, 0, 0);
    }

    // ---- Phase A: gelu-x for row r (c = channel, 12-col group) ----
    {
        const int c = tid >> 3, colg = tid & 7, j0 = colg * 12;

        float w[9];
        #pragma unroll
        for (int i = 0; i < 9; ++i) w[i] = wx[c * 9 + i];
        const float bias = bx[c];

        float acc[12], winc[12];
        #pragma unroll
        for (int jj = 0; jj < 12; ++jj) acc[jj] = bias;

        const float* xb = x + (size_t)(b * 64 + c) * 9216;
        #pragma unroll
        for (int dr = 0; dr < 3; ++dr) {
            const int rr = r + dr - 1;
            const bool rok = (rr >= 0) && (rr < 96);
            float f[20];
            #pragma unroll
            for (int m = 0; m < 5; ++m) {
                const int cs = j0 - 4 + 4 * m;
                float4 v = make_float4(0.f, 0.f, 0.f, 0.f);
                if (rok && cs >= 0 && cs <= 92)
                    v = *(const float4*)(xb + rr * 96 + cs);
                f[4 * m] = v.x; f[4 * m + 1] = v.y;
                f[4 * m + 2] = v.z; f[4 * m + 3] = v.w;
            }
            #pragma unroll
            for (int jj = 0; jj < 12; ++jj)
                acc[jj] += f[jj + 3] * w[dr * 3] + f[jj + 4] * w[dr * 3 + 1]
                         + f[jj + 5] * w[dr * 3 + 2];
            if (dr == 1) {
                #pragma unroll
                for (int jj = 0; jj < 12; ++jj) winc[jj] = f[jj + 4];  // residual
            }
        }

        const int g = c >> 5, cl = c & 31, chunk = cl >> 3, pos = cl & 7;
        #pragma unroll
        for (int jj = 0; jj < 12; ++jj) {
            const float gv = gelu_fast(acc[jj] + winc[jj]);
            const int T = j0 + jj + 8;
            const int schunk = chunk ^ ((T >> 1) & 3);
            rowbuf[g * 4096 + T * 32 + schunk * 8 + pos] = f2bf(gv);
        }
    }
    __syncthreads();

    // ---- Phase B: MFMA, wave w < 7 owns j-tile j0a = 16*w ----
    const int wave = tid >> 6;
    const int lane = tid & 63;
    const int n    = lane & 15;   // u (B col) == A row within tile
    const int q    = lane >> 4;   // k-chunk / C row-group
    if (wave < 7) {
        const int j0a = wave * 16;
        const ushortT* zb = zbuf + (size_t)b * 16384;
        const ushortT* rb = rowbuf;
        f32x4 acc0 = {0.f, 0.f, 0.f, 0.f};

        #pragma unroll
        for (int g = 0; g < 2; ++g) {
            bf16x8 bfrag[16];
            #pragma unroll
            for (int v = 0; v < 16; ++v)
                bfrag[v] = *(const bf16x8*)(zb + (v * 16 + n) * 64 + g * 32 + 8 * q);
            #pragma unroll
            for (int v = 0; v < 16; ++v) {
                const int T = j0a + n + v;
                const int off = (g * 128 + T) * 32 + ((q ^ ((T >> 1) & 3)) << 3);
                const bf16x8 a0 = *(const bf16x8*)(rb + off);
                acc0 = __builtin_amdgcn_mfma_f32_16x16x32_bf16(a0, bfrag[v], acc0, 0, 0, 0);
            }
        }

        // write-once scatter: C elem (m=4q+g3, u=n) -> outacc[ii=15-u][j0a+m]
        const int ii = 15 - n;
        float* orow = outacc + ii * 113 + j0a + 4 * q;
        #pragma unroll
        for (int g3 = 0; g3 < 4; ++g3) orow[g3] = acc0[g3];
    }
    __syncthreads();

    // ---- Phase C: out[b][i = r-7+ii][j] += outacc[ii][j], i,j in [0,97) ----
    float* outb = out + (size_t)b * 9409;
    #pragma unroll
    for (int p = 0; p < 4; ++p) {
        const int ii = p * 4 + (tid >> 7);
        const int j  = tid & 127;
        const int irow = r - 7 + ii;
        if (j < 97 && irow >= 0 && irow < 97)
            atomicAdd(&outb[irow * 97 + j], outacc[ii * 113 + j] * OUT_SCALE);
    }
}

// ---------------------------------------------------------------------------
extern "C" void kernel_launch(void* const* d_in, const int* in_sizes, int n_in,
                              void* d_out, int out_size, void* d_ws, size_t ws_size,
                              hipStream_t stream)
{
    const float* z  = (const float*)d_in[0];
    const float* x  = (const float*)d_in[1];
    const float* wz = (const float*)d_in[2];
    const float* bz = (const float*)d_in[3];
    const float* wx = (const float*)d_in[4];
    const float* bx = (const float*)d_in[5];
    float* out = (float*)d_out;

    // workspace: only ZB (2 MB) now — XgT round-trip eliminated
    ushortT* zbuf = (ushortT*)d_ws;

    hipMemsetAsync(d_out, 0, (size_t)out_size * 4, stream);

    k_gelu_z<<<dim3(64), 256, 0, stream>>>(z, wz, bz, zbuf);
    k_fused<<<dim3(6144), 512, 0, stream>>>(x, wx, bx, zbuf, out);

    (void)in_sizes; (void)n_in; (void)ws_size;
}

// Round 3
// 348.643 us; speedup vs baseline: 1.1577x; 1.1577x over previous
//
#include <hip/hip_runtime.h>
#include <hip/hip_bf16.h>

typedef unsigned short ushortT;
typedef __bf16 bf16x8 __attribute__((ext_vector_type(8)));
typedef float f32x4 __attribute__((ext_vector_type(4)));

#define OUT_SCALE 0.001f

// fast GELU: v * sigmoid(1.5957691*(v + 0.044715 v^3)); |err vs exact| <~1e-3
__device__ __forceinline__ float gelu_fast(float v) {
    const float u = v * fmaf(0.044715f * v, v, 1.0f);
    const float e = __expf(-1.5957691216057308f * u);
    return v * __builtin_amdgcn_rcpf(1.0f + e);
}
__device__ __forceinline__ ushortT f2bf(float f) {
    __hip_bfloat16 h = __float2bfloat16(f);
    return *reinterpret_cast<ushortT*>(&h);
}

// ---------------------------------------------------------------------------
// K2: z path. gelu(z + dwconv3x3(z) + b) written as bf16 ZB[b][v][u][c64]
// (unchanged, verified)
// ---------------------------------------------------------------------------
__global__ __launch_bounds__(256) void k_gelu_z(
    const float* __restrict__ z, const float* __restrict__ wz,
    const float* __restrict__ bz, ushortT* __restrict__ zbuf)
{
    const int b   = blockIdx.x;
    const int tid = threadIdx.x;
    const int c   = tid >> 2;
    const int q   = tid & 3;

    __shared__ float   zs[64 * 260];
    __shared__ ushortT zt[16384];

    {
        const float4* src = (const float4*)(z + ((size_t)b * 64 + c) * 256 + q * 64);
        float4* dstv = (float4*)(zs + c * 260 + q * 64);
        #pragma unroll
        for (int i = 0; i < 16; ++i) dstv[i] = src[i];
    }
    __syncthreads();

    const float* wp = wz + c * 9;
    float w[9];
    #pragma unroll
    for (int i = 0; i < 9; ++i) w[i] = wp[i];
    const float bias = bz[c];
    const float* zc = zs + c * 260;

    for (int v = q * 4; v < q * 4 + 4; ++v) {
        #pragma unroll
        for (int u = 0; u < 16; ++u) {
            float acc = bias;
            #pragma unroll
            for (int dr = 0; dr < 3; ++dr) {
                const int uu = u + dr - 1;
                if (uu < 0 || uu >= 16) continue;
                #pragma unroll
                for (int dc = 0; dc < 3; ++dc) {
                    const int vv = v + dc - 1;
                    if (vv < 0 || vv >= 16) continue;
                    acc += zc[uu * 16 + vv] * w[dr * 3 + dc];
                }
            }
            const float y = acc + zc[u * 16 + v];
            zt[(v * 16 + u) * 64 + c] = f2bf(gelu_fast(y));
        }
    }
    __syncthreads();
    uint4* dst = (uint4*)(zbuf + (size_t)b * 16384);
    const uint4* s4 = (const uint4*)zt;
    for (int i = tid; i < 2048; i += 256) dst[i] = s4[i];
}

// ---------------------------------------------------------------------------
// K-fused (R=4): gelu-x + correlation, NO global atomics.
// Block (b, k) handles rows r0=4k..4k+3 in 2 super-phases of 2 rows:
//   Phase A: 512 thr compute gelu(x+dwconv+b) rows -> swizzled rowbuf[2] LDS
//   Phase B: waves 0..6, per g-phase load 16 B-frags once, 16 MFMA per row,
//            accumulate (+=) into LDS outacc band (19x97; wave owns 16 cols)
// Epilogue: plain coalesced store of the band to part[b][k] (disjoint slabs).
// ---------------------------------------------------------------------------
__global__ __launch_bounds__(512, 4) void k_fused(
    const float* __restrict__ x, const float* __restrict__ wx,
    const float* __restrict__ bx, const ushortT* __restrict__ zbuf,
    float* __restrict__ part)
{
    // bijective XCD swizzle: 1536 blocks = 8 * 192; same-b adjacent-k per XCD
    const int lin = blockIdx.x;
    const int sw  = ((lin & 7) * 192) + (lin >> 3);
    const int k   = sw % 24;
    const int b   = sw / 24;
    const int r0  = k * 4;
    const int tid = threadIdx.x;

    __shared__ ushortT rowbuf[2][8192];   // per row: [g2][T128][c32 swizzled]
    __shared__ float   outacc[19 * 113];  // band accumulator (pad to 113)

    // zero outacc (2147 floats)
    for (int i = tid; i < 19 * 113; i += 512) outacc[i] = 0.f;

    // zero-pad rowbuf bands T in [0,8) and [104,128) for both rloc x g: 512 uint4
    {
        const int rrg = tid >> 7, t = tid & 127;
        const int off = (t < 32) ? t * 8 : 3328 + (t - 32) * 8;
        *(uint4*)(&rowbuf[0][0] + rrg * 4096 + off) = make_uint4(0, 0, 0, 0);
    }

    const int c = tid >> 3, colg = tid & 7, j0 = colg * 12;
    const int wave = tid >> 6;
    const int lane = tid & 63;
    const int n    = lane & 15;   // u (B col) == A row within tile
    const int q    = lane >> 4;   // k-chunk / C row-group
    const int j0a  = wave * 16;   // waves 0..6 own j-tiles

    float w[9];
    #pragma unroll
    for (int i = 0; i < 9; ++i) w[i] = wx[c * 9 + i];
    const float bias = bx[c];
    const float* xb = x + (size_t)(b * 64 + c) * 9216;
    const ushortT* zb = zbuf + (size_t)b * 16384;

    const int g_  = c >> 5, cl = c & 31, chunk = cl >> 3, pos = cl & 7;

    #pragma unroll
    for (int sp = 0; sp < 2; ++sp) {
        // ---- Phase A: 2 gelu rows into rowbuf[0..1] ----
        #pragma unroll
        for (int rloc = 0; rloc < 2; ++rloc) {
            const int r = r0 + sp * 2 + rloc;
            float acc[12], winc[12];
            #pragma unroll
            for (int jj = 0; jj < 12; ++jj) acc[jj] = bias;
            #pragma unroll
            for (int dr = 0; dr < 3; ++dr) {
                const int rr = r + dr - 1;
                const bool rok = (rr >= 0) && (rr < 96);
                float f[20];
                #pragma unroll
                for (int m = 0; m < 5; ++m) {
                    const int cs = j0 - 4 + 4 * m;
                    float4 v = make_float4(0.f, 0.f, 0.f, 0.f);
                    if (rok && cs >= 0 && cs <= 92)
                        v = *(const float4*)(xb + rr * 96 + cs);
                    f[4 * m] = v.x; f[4 * m + 1] = v.y;
                    f[4 * m + 2] = v.z; f[4 * m + 3] = v.w;
                }
                #pragma unroll
                for (int jj = 0; jj < 12; ++jj)
                    acc[jj] += f[jj + 3] * w[dr * 3] + f[jj + 4] * w[dr * 3 + 1]
                             + f[jj + 5] * w[dr * 3 + 2];
                if (dr == 1) {
                    #pragma unroll
                    for (int jj = 0; jj < 12; ++jj) winc[jj] = f[jj + 4];
                }
            }
            ushortT* rbw = &rowbuf[rloc][0] + g_ * 4096;
            #pragma unroll
            for (int jj = 0; jj < 12; ++jj) {
                const float gv = gelu_fast(acc[jj] + winc[jj]);
                const int T = j0 + jj + 8;
                const int schunk = chunk ^ ((T >> 1) & 3);
                rbw[T * 32 + schunk * 8 + pos] = f2bf(gv);
            }
        }
        __syncthreads();

        // ---- Phase B: MFMA, waves 0..6; B-frags loaded once per g ----
        if (wave < 7) {
            f32x4 acc0 = {0.f, 0.f, 0.f, 0.f};
            f32x4 acc1 = {0.f, 0.f, 0.f, 0.f};
            #pragma unroll
            for (int g = 0; g < 2; ++g) {
                bf16x8 bfrag[16];
                #pragma unroll
                for (int v = 0; v < 16; ++v)
                    bfrag[v] = *(const bf16x8*)(zb + (v * 16 + n) * 64 + g * 32 + 8 * q);
                #pragma unroll
                for (int v = 0; v < 16; ++v) {
                    const int T = j0a + n + v;
                    const int off = (g * 128 + T) * 32 + ((q ^ ((T >> 1) & 3)) << 3);
                    const bf16x8 a0 = *(const bf16x8*)(&rowbuf[0][0] + off);
                    acc0 = __builtin_amdgcn_mfma_f32_16x16x32_bf16(a0, bfrag[v], acc0, 0, 0, 0);
                    const bf16x8 a1 = *(const bf16x8*)(&rowbuf[1][0] + off);
                    acc1 = __builtin_amdgcn_mfma_f32_16x16x32_bf16(a1, bfrag[v], acc1, 0, 0, 0);
                }
            }
            // accumulate into band: row (sp*2+rloc) contributes to ii=(sp*2+rloc)+15-n
            const int iib = sp * 2 + 15 - n;
            float* orow0 = outacc + iib * 113 + j0a + 4 * q;
            float* orow1 = outacc + (iib + 1) * 113 + j0a + 4 * q;
            #pragma unroll
            for (int g3 = 0; g3 < 4; ++g3) orow0[g3] += acc0[g3];
            #pragma unroll
            for (int g3 = 0; g3 < 4; ++g3) orow1[g3] += acc1[g3];
        }
        __syncthreads();
    }

    // ---- Epilogue: plain stores of 19x97 band to part[b][k] ----
    float* pb = part + (size_t)(b * 24 + k) * (19 * 97);
    for (int i = tid; i < 19 * 97; i += 512) {
        const int ii = i / 97, j = i - ii * 97;
        pb[i] = outacc[ii * 113 + j] * OUT_SCALE;
    }
}

// ---------------------------------------------------------------------------
// K-reduce: out[b][i][j] = sum_k part[b][k][i-4k+7][j]   (<=5 terms)
// one thread per output element; no atomics, writes out directly (no memset)
// ---------------------------------------------------------------------------
__global__ __launch_bounds__(256) void k_reduce(
    const float* __restrict__ part, float* __restrict__ out)
{
    const int gid = blockIdx.x * 256 + threadIdx.x;
    if (gid >= 64 * 9409) return;
    const int b   = gid / 9409;
    const int rem = gid - b * 9409;
    const int i   = rem / 97;
    const int j   = rem - i * 97;

    const int klo = (i >= 11) ? ((i - 8) >> 2) : 0;   // ceil((i-11)/4)
    int khi = (i + 7) >> 2;
    if (khi > 23) khi = 23;

    float s = 0.f;
    const float* pb = part + (size_t)b * 24 * 19 * 97;
    for (int k = klo; k <= khi; ++k) {
        const int ib = i - 4 * k + 7;
        s += pb[(k * 19 + ib) * 97 + j];
    }
    out[(size_t)b * 9409 + rem] = s;
}

// ---------------------------------------------------------------------------
extern "C" void kernel_launch(void* const* d_in, const int* in_sizes, int n_in,
                              void* d_out, int out_size, void* d_ws, size_t ws_size,
                              hipStream_t stream)
{
    const float* z  = (const float*)d_in[0];
    const float* x  = (const float*)d_in[1];
    const float* wz = (const float*)d_in[2];
    const float* bz = (const float*)d_in[3];
    const float* wx = (const float*)d_in[4];
    const float* bx = (const float*)d_in[5];
    float* out = (float*)d_out;

    // workspace: ZB (2 MB) then part bands (1536 * 19*97 * 4 B = 11.3 MB)
    ushortT* zbuf = (ushortT*)d_ws;
    float*   partw = (float*)((char*)d_ws + (size_t)64 * 16384 * 2);

    k_gelu_z<<<dim3(64), 256, 0, stream>>>(z, wz, bz, zbuf);
    k_fused<<<dim3(1536), 512, 0, stream>>>(x, wx, bx, zbuf, partw);
    const int nout = 64 * 9409;
    k_reduce<<<dim3((nout + 255) / 256), 256, 0, stream>>>(partw, out);

    (void)in_sizes; (void)n_in; (void)ws_size; (void)out_size;
}

// Round 4
// 331.983 us; speedup vs baseline: 1.2158x; 1.0502x over previous
//
#include <hip/hip_runtime.h>
#include <hip/hip_bf16.h>

typedef unsigned short ushortT;
typedef __bf16 bf16x8 __attribute__((ext_vector_type(8)));
typedef float f32x4 __attribute__((ext_vector_type(4)));

#define OUT_SCALE 0.001f

// fast GELU: v * sigmoid(1.5957691*(v + 0.044715 v^3)); |err vs exact| <~1e-3
__device__ __forceinline__ float gelu_fast(float v) {
    const float u = v * fmaf(0.044715f * v, v, 1.0f);
    const float e = __expf(-1.5957691216057308f * u);
    return v * __builtin_amdgcn_rcpf(1.0f + e);
}
__device__ __forceinline__ ushortT f2bf(float f) {
    __hip_bfloat16 h = __float2bfloat16(f);
    return *reinterpret_cast<ushortT*>(&h);
}

// ---------------------------------------------------------------------------
// K2: z path, split per 16 channels. grid (64,4), 256 thr, LDS 16.6 KB.
// gelu(z + dwconv3x3(z) + b) -> bf16 ZB[b][v][u][c64]
// ---------------------------------------------------------------------------
__global__ __launch_bounds__(256) void k_gelu_z(
    const float* __restrict__ z, const float* __restrict__ wz,
    const float* __restrict__ bz, ushortT* __restrict__ zbuf)
{
    const int b  = blockIdx.x;
    const int cg = blockIdx.y;        // channel group of 16
    const int tid = threadIdx.x;

    __shared__ float zs[16 * 260];    // 16 ch x 256 (+4 pad)

    for (int i = tid; i < 1024; i += 256) {
        const int c_l = i >> 6, pos = i & 63;
        *(float4*)(zs + c_l * 260 + pos * 4) =
            *(const float4*)(z + ((size_t)(b * 64 + cg * 16 + c_l)) * 256 + pos * 4);
    }
    __syncthreads();

    const int c_l = tid & 15;         // local channel
    const int v   = tid >> 4;         // search col (0..15)
    const int c   = cg * 16 + c_l;

    float w[9];
    #pragma unroll
    for (int i = 0; i < 9; ++i) w[i] = wz[c * 9 + i];
    const float bias = bz[c];
    const float* zc = zs + c_l * 260;
    ushortT* zo = zbuf + (size_t)b * 16384 + c;

    #pragma unroll
    for (int u = 0; u < 16; ++u) {
        float acc = bias;
        #pragma unroll
        for (int dr = 0; dr < 3; ++dr) {
            const int uu = u + dr - 1;
            if (uu < 0 || uu >= 16) continue;
            #pragma unroll
            for (int dc = 0; dc < 3; ++dc) {
                const int vv = v + dc - 1;
                if (vv < 0 || vv >= 16) continue;
                acc += zc[uu * 16 + vv] * w[dr * 3 + dc];
            }
        }
        const float y = acc + zc[u * 16 + v];
        zo[(v * 16 + u) * 64] = f2bf(gelu_fast(y));
    }
}

// ---------------------------------------------------------------------------
// K-fused (R=2): gelu-x + correlation, ONE barrier, no LDS accumulator.
// Block (b,k2) owns rows r0=2k2, r0+1.
//   Phase A (512 thr): gelu(x+dwconv+b) for both rows -> swizzled rowbuf[2]
//   barrier
//   Phase B (waves 0..6): per g load 16 B-frags once, per v 2 ds_read+2 MFMA;
//   store acc f32x4 straight to part[b][r][ii][112] (disjoint, no atomics).
// ---------------------------------------------------------------------------
__global__ __launch_bounds__(512, 4) void k_fused(
    const float* __restrict__ x, const float* __restrict__ wx,
    const float* __restrict__ bx, const ushortT* __restrict__ zbuf,
    float* __restrict__ part)
{
    // bijective XCD swizzle: 3072 = 8 * 384; XCD i gets b in [8i, 8i+8)
    const int lin = blockIdx.x;
    const int sw  = ((lin & 7) * 384) + (lin >> 3);
    const int k2  = sw % 48;
    const int b   = sw / 48;
    const int r0  = k2 * 2;
    const int tid = threadIdx.x;

    __shared__ ushortT rowbuf[2][8192];   // per row: [g2][T128][c32 swizzled]

    // zero-pad T in [0,8) and [104,128) for rows x g: 512 uint4, one/thread
    {
        const int row = tid >> 8, g = (tid >> 7) & 1, t = tid & 127;
        const int off = (t < 32) ? t * 8 : 3328 + (t - 32) * 8;
        *(uint4*)(&rowbuf[row][g * 4096 + off]) = make_uint4(0, 0, 0, 0);
    }

    const int c = tid >> 3, colg = tid & 7, j0 = colg * 12;
    const int g_ = c >> 5, cl = c & 31, chunk = cl >> 3, pos = cl & 7;

    float w[9];
    #pragma unroll
    for (int i = 0; i < 9; ++i) w[i] = wx[c * 9 + i];
    const float bias = bx[c];
    const float* xb = x + (size_t)(b * 64 + c) * 9216;

    // ---- Phase A: 2 gelu rows into rowbuf[0..1] ----
    #pragma unroll
    for (int rloc = 0; rloc < 2; ++rloc) {
        const int r = r0 + rloc;
        float acc[12], winc[12];
        #pragma unroll
        for (int jj = 0; jj < 12; ++jj) acc[jj] = bias;
        #pragma unroll
        for (int dr = 0; dr < 3; ++dr) {
            const int rr = r + dr - 1;
            const bool rok = (rr >= 0) && (rr < 96);
            float f[20];
            #pragma unroll
            for (int m = 0; m < 5; ++m) {
                const int cs = j0 - 4 + 4 * m;
                float4 v = make_float4(0.f, 0.f, 0.f, 0.f);
                if (rok && cs >= 0 && cs <= 92)
                    v = *(const float4*)(xb + rr * 96 + cs);
                f[4 * m] = v.x; f[4 * m + 1] = v.y;
                f[4 * m + 2] = v.z; f[4 * m + 3] = v.w;
            }
            #pragma unroll
            for (int jj = 0; jj < 12; ++jj)
                acc[jj] += f[jj + 3] * w[dr * 3] + f[jj + 4] * w[dr * 3 + 1]
                         + f[jj + 5] * w[dr * 3 + 2];
            if (dr == 1) {
                #pragma unroll
                for (int jj = 0; jj < 12; ++jj) winc[jj] = f[jj + 4];  // residual
            }
        }
        ushortT* rbw = &rowbuf[rloc][0] + g_ * 4096;
        #pragma unroll
        for (int jj = 0; jj < 12; ++jj) {
            const float gv = gelu_fast(acc[jj] + winc[jj]);
            const int T = j0 + jj + 8;
            const int schunk = chunk ^ ((T >> 1) & 3);
            rbw[T * 32 + schunk * 8 + pos] = f2bf(gv);
        }
    }
    __syncthreads();

    // ---- Phase B: MFMA, waves 0..6 own j-tile j0a = 16*wave ----
    const int wave = tid >> 6;
    const int lane = tid & 63;
    const int n    = lane & 15;   // u (B col) == A row within tile
    const int q    = lane >> 4;   // k-chunk / C row-group
    if (wave < 7) {
        const int j0a = wave * 16;
        const ushortT* zb = zbuf + (size_t)b * 16384;
        f32x4 acc0 = {0.f, 0.f, 0.f, 0.f};
        f32x4 acc1 = {0.f, 0.f, 0.f, 0.f};

        #pragma unroll
        for (int g = 0; g < 2; ++g) {
            bf16x8 bfrag[16];
            #pragma unroll
            for (int v = 0; v < 16; ++v)
                bfrag[v] = *(const bf16x8*)(zb + (v * 16 + n) * 64 + g * 32 + 8 * q);
            #pragma unroll
            for (int v = 0; v < 16; ++v) {
                const int T = j0a + n + v;
                const int off = (g * 128 + T) * 32 + ((q ^ ((T >> 1) & 3)) << 3);
                const bf16x8 a0 = *(const bf16x8*)(&rowbuf[0][0] + off);
                acc0 = __builtin_amdgcn_mfma_f32_16x16x32_bf16(a0, bfrag[v], acc0, 0, 0, 0);
                const bf16x8 a1 = *(const bf16x8*)(&rowbuf[1][0] + off);
                acc1 = __builtin_amdgcn_mfma_f32_16x16x32_bf16(a1, bfrag[v], acc1, 0, 0, 0);
            }
        }

        // direct stores: part[b][r][ii=15-n][j0a+4q .. +3], disjoint per lane
        const int ii = 15 - n;
        const int joff = j0a + 4 * q;
        f32x4* p0 = (f32x4*)(part + ((size_t)(b * 96 + r0) * 16 + ii) * 112 + joff);
        *p0 = acc0;
        f32x4* p1 = (f32x4*)(part + ((size_t)(b * 96 + r0 + 1) * 16 + ii) * 112 + joff);
        *p1 = acc1;
    }
}

// ---------------------------------------------------------------------------
// K-reduce: out[b][i][j] = OUT_SCALE * sum_r part[b][r][i-r+7][j],
// r in [max(0,i-8), min(95,i+7)] (<=16 terms). One thread per output elem.
// ---------------------------------------------------------------------------
__global__ __launch_bounds__(256) void k_reduce(
    const float* __restrict__ part, float* __restrict__ out)
{
    const int gid = blockIdx.x * 256 + threadIdx.x;
    if (gid >= 64 * 9409) return;
    const int b   = gid / 9409;
    const int rem = gid - b * 9409;
    const int i   = rem / 97;
    const int j   = rem - i * 97;

    int rlo = i - 8;  if (rlo < 0)  rlo = 0;
    int rhi = i + 7;  if (rhi > 95) rhi = 95;

    // index ((b*96 + r)*16 + (i-r+7))*112 + j ; per r++ delta = 16*112-112 = 1680
    const float* p = part + ((size_t)(b * 96 + rlo) * 16 + (i - rlo + 7)) * 112 + j;
    float s = 0.f;
    for (int r = rlo; r <= rhi; ++r) {
        s += *p;
        p += 1680;
    }
    out[(size_t)b * 9409 + rem] = s * OUT_SCALE;
}

// ---------------------------------------------------------------------------
extern "C" void kernel_launch(void* const* d_in, const int* in_sizes, int n_in,
                              void* d_out, int out_size, void* d_ws, size_t ws_size,
                              hipStream_t stream)
{
    const float* z  = (const float*)d_in[0];
    const float* x  = (const float*)d_in[1];
    const float* wz = (const float*)d_in[2];
    const float* bz = (const float*)d_in[3];
    const float* wx = (const float*)d_in[4];
    const float* bx = (const float*)d_in[5];
    float* out = (float*)d_out;

    // workspace: ZB (2 MB) then part[64][96][16][112] f32 (44.04 MB)
    ushortT* zbuf = (ushortT*)d_ws;
    float*   partw = (float*)((char*)d_ws + (size_t)64 * 16384 * 2);

    k_gelu_z<<<dim3(64, 4), 256, 0, stream>>>(z, wz, bz, zbuf);
    k_fused<<<dim3(3072), 512, 0, stream>>>(x, wx, bx, zbuf, partw);
    const int nout = 64 * 9409;
    k_reduce<<<dim3((nout + 255) / 256), 256, 0, stream>>>(partw, out);

    (void)in_sizes; (void)n_in; (void)ws_size; (void)out_size;
}

// Round 5
// 324.692 us; speedup vs baseline: 1.2431x; 1.0225x over previous
//
#include <hip/hip_runtime.h>
#include <hip/hip_bf16.h>

typedef unsigned short ushortT;
typedef __bf16 bf16x8 __attribute__((ext_vector_type(8)));
typedef float f32x4 __attribute__((ext_vector_type(4)));

#define OUT_SCALE 0.001f

// fast GELU: v * sigmoid(1.5957691*(v + 0.044715 v^3)); |err vs exact| <~1e-3
__device__ __forceinline__ float gelu_fast(float v) {
    const float u = v * fmaf(0.044715f * v, v, 1.0f);
    const float e = __expf(-1.5957691216057308f * u);
    return v * __builtin_amdgcn_rcpf(1.0f + e);
}
__device__ __forceinline__ ushortT f2bf(float f) {
    __hip_bfloat16 h = __float2bfloat16(f);
    return *reinterpret_cast<ushortT*>(&h);
}

// ---------------------------------------------------------------------------
// K2: z path, split per 16 channels. grid (64,4), 256 thr, LDS 16.6 KB.
// gelu(z + dwconv3x3(z) + b) -> bf16 ZB[b][v][u][c64]
// ---------------------------------------------------------------------------
__global__ __launch_bounds__(256) void k_gelu_z(
    const float* __restrict__ z, const float* __restrict__ wz,
    const float* __restrict__ bz, ushortT* __restrict__ zbuf)
{
    const int b  = blockIdx.x;
    const int cg = blockIdx.y;        // channel group of 16
    const int tid = threadIdx.x;

    __shared__ float zs[16 * 260];    // 16 ch x 256 (+4 pad)

    for (int i = tid; i < 1024; i += 256) {
        const int c_l = i >> 6, pos = i & 63;
        *(float4*)(zs + c_l * 260 + pos * 4) =
            *(const float4*)(z + ((size_t)(b * 64 + cg * 16 + c_l)) * 256 + pos * 4);
    }
    __syncthreads();

    const int c_l = tid & 15;         // local channel
    const int v   = tid >> 4;         // search col (0..15)
    const int c   = cg * 16 + c_l;

    float w[9];
    #pragma unroll
    for (int i = 0; i < 9; ++i) w[i] = wz[c * 9 + i];
    const float bias = bz[c];
    const float* zc = zs + c_l * 260;
    ushortT* zo = zbuf + (size_t)b * 16384 + c;

    #pragma unroll
    for (int u = 0; u < 16; ++u) {
        float acc = bias;
        #pragma unroll
        for (int dr = 0; dr < 3; ++dr) {
            const int uu = u + dr - 1;
            if (uu < 0 || uu >= 16) continue;
            #pragma unroll
            for (int dc = 0; dc < 3; ++dc) {
                const int vv = v + dc - 1;
                if (vv < 0 || vv >= 16) continue;
                acc += zc[uu * 16 + vv] * w[dr * 3 + dc];
            }
        }
        const float y = acc + zc[u * 16 + v];
        zo[(v * 16 + u) * 64] = f2bf(gelu_fast(y));
    }
}

// ---------------------------------------------------------------------------
// K-fused (R=2): gelu-x + correlation, ONE barrier, no LDS accumulator.
// Phase A: branchless clamped loads, 4 input rows loaded ONCE (20 float4),
// horizontal 3-tap convs feed both output-row accumulators; residual folded.
// Phase B: waves 0..6, per g load 16 B-frags once, 2 ds_read+2 MFMA per v;
// f32x4 stores straight to part[b][r][ii][112] (disjoint, no atomics).
// ---------------------------------------------------------------------------
__global__ __launch_bounds__(512, 4) void k_fused(
    const float* __restrict__ x, const float* __restrict__ wx,
    const float* __restrict__ bx, const ushortT* __restrict__ zbuf,
    float* __restrict__ part)
{
    // bijective XCD swizzle: 3072 = 8 * 384; XCD i gets b in [8i, 8i+8)
    const int lin = blockIdx.x;
    const int sw  = ((lin & 7) * 384) + (lin >> 3);
    const int k2  = sw % 48;
    const int b   = sw / 48;
    const int r0  = k2 * 2;
    const int tid = threadIdx.x;

    __shared__ ushortT rowbuf[2][8192];   // per row: [g2][T128][c32 swizzled]

    // zero-pad T in [0,8) and [104,128) for rows x g: 512 uint4, one/thread
    {
        const int row = tid >> 8, g = (tid >> 7) & 1, t = tid & 127;
        const int off = (t < 32) ? t * 8 : 3328 + (t - 32) * 8;
        *(uint4*)(&rowbuf[row][g * 4096 + off]) = make_uint4(0, 0, 0, 0);
    }

    // ---- Phase A ----
    {
        const int c = tid >> 3, colg = tid & 7, j0 = colg * 12;
        const int g_ = c >> 5, cl = c & 31, chunk = cl >> 3, pos = cl & 7;

        float w[9];
        #pragma unroll
        for (int i = 0; i < 9; ++i) w[i] = wx[c * 9 + i];
        const float bias = bx[c];
        const float* xb = x + (size_t)(b * 64 + c) * 9216;

        float acc0[12], acc1[12];
        #pragma unroll
        for (int jj = 0; jj < 12; ++jj) { acc0[jj] = bias; acc1[jj] = bias; }

        // input rows r0-1 .. r0+2, each loaded once (branchless, clamped)
        #pragma unroll
        for (int s = 0; s < 4; ++s) {
            const int rr  = r0 - 1 + s;
            const int rcl = (rr < 0) ? 0 : (rr > 95 ? 95 : rr);
            const bool rok = (rr >= 0) && (rr < 96);
            float f[20];
            #pragma unroll
            for (int m = 0; m < 5; ++m) {
                const int cs  = j0 - 4 + 4 * m;
                const int csc = (cs < 0) ? 0 : (cs > 92 ? 92 : cs);
                const float4 v = *(const float4*)(xb + rcl * 96 + csc);
                const bool ok = rok && (cs >= 0) && (cs <= 92);
                f[4 * m + 0] = ok ? v.x : 0.f;
                f[4 * m + 1] = ok ? v.y : 0.f;
                f[4 * m + 2] = ok ? v.z : 0.f;
                f[4 * m + 3] = ok ? v.w : 0.f;
            }
            if (s == 0) {
                #pragma unroll
                for (int jj = 0; jj < 12; ++jj)
                    acc0[jj] += f[jj+3]*w[0] + f[jj+4]*w[1] + f[jj+5]*w[2];
            } else if (s == 1) {
                #pragma unroll
                for (int jj = 0; jj < 12; ++jj) {
                    acc0[jj] += f[jj+3]*w[3] + f[jj+4]*w[4] + f[jj+5]*w[5]
                              + f[jj+4];                       // residual row r0
                    acc1[jj] += f[jj+3]*w[0] + f[jj+4]*w[1] + f[jj+5]*w[2];
                }
            } else if (s == 2) {
                #pragma unroll
                for (int jj = 0; jj < 12; ++jj) {
                    acc0[jj] += f[jj+3]*w[6] + f[jj+4]*w[7] + f[jj+5]*w[8];
                    acc1[jj] += f[jj+3]*w[3] + f[jj+4]*w[4] + f[jj+5]*w[5]
                              + f[jj+4];                       // residual row r0+1
                }
            } else {
                #pragma unroll
                for (int jj = 0; jj < 12; ++jj)
                    acc1[jj] += f[jj+3]*w[6] + f[jj+4]*w[7] + f[jj+5]*w[8];
            }
        }

        ushortT* rbw0 = &rowbuf[0][0] + g_ * 4096;
        ushortT* rbw1 = &rowbuf[1][0] + g_ * 4096;
        #pragma unroll
        for (int jj = 0; jj < 12; ++jj) {
            const int T  = j0 + jj + 8;
            const int sh = T * 32 + ((chunk ^ ((T >> 1) & 3)) << 3) + pos;
            rbw0[sh] = f2bf(gelu_fast(acc0[jj]));
            rbw1[sh] = f2bf(gelu_fast(acc1[jj]));
        }
    }
    __syncthreads();

    // ---- Phase B: MFMA, waves 0..6 own j-tile j0a = 16*wave ----
    const int wave = tid >> 6;
    const int lane = tid & 63;
    const int n    = lane & 15;   // u (B col) == A row within tile
    const int q    = lane >> 4;   // k-chunk / C row-group
    if (wave < 7) {
        const int j0a = wave * 16;
        const ushortT* zb = zbuf + (size_t)b * 16384;
        f32x4 acc0 = {0.f, 0.f, 0.f, 0.f};
        f32x4 acc1 = {0.f, 0.f, 0.f, 0.f};

        #pragma unroll
        for (int g = 0; g < 2; ++g) {
            bf16x8 bfrag[16];
            #pragma unroll
            for (int v = 0; v < 16; ++v)
                bfrag[v] = *(const bf16x8*)(zb + (v * 16 + n) * 64 + g * 32 + 8 * q);
            #pragma unroll
            for (int v = 0; v < 16; ++v) {
                const int T = j0a + n + v;
                const int off = (g * 128 + T) * 32 + ((q ^ ((T >> 1) & 3)) << 3);
                const bf16x8 a0 = *(const bf16x8*)(&rowbuf[0][0] + off);
                acc0 = __builtin_amdgcn_mfma_f32_16x16x32_bf16(a0, bfrag[v], acc0, 0, 0, 0);
                const bf16x8 a1 = *(const bf16x8*)(&rowbuf[1][0] + off);
                acc1 = __builtin_amdgcn_mfma_f32_16x16x32_bf16(a1, bfrag[v], acc1, 0, 0, 0);
            }
        }

        // direct stores: part[b][r][ii=15-n][j0a+4q .. +3], disjoint per lane
        const int ii = 15 - n;
        const int joff = j0a + 4 * q;
        f32x4* p0 = (f32x4*)(part + ((size_t)(b * 96 + r0) * 16 + ii) * 112 + joff);
        *p0 = acc0;
        f32x4* p1 = (f32x4*)(part + ((size_t)(b * 96 + r0 + 1) * 16 + ii) * 112 + joff);
        *p1 = acc1;
    }
}

// ---------------------------------------------------------------------------
// K-reduce (vectorized): out[b][i][4j4..] = OUT_SCALE * sum_r part band rows.
// Each thread: 4 consecutive j via f32x4 band loads (<=16 terms).
// ---------------------------------------------------------------------------
__global__ __launch_bounds__(256) void k_reduce(
    const float* __restrict__ part, float* __restrict__ out)
{
    const int gid = blockIdx.x * 256 + threadIdx.x;
    if (gid >= 64 * 97 * 25) return;
    const int j4 = gid % 25;
    const int t  = gid / 25;
    const int i  = t % 97;
    const int b  = t / 97;
    const int j  = j4 * 4;

    int rlo = i - 8;  if (rlo < 0)  rlo = 0;
    int rhi = i + 7;  if (rhi > 95) rhi = 95;

    // index ((b*96 + r)*16 + (i-r+7))*112 + j ; per r++ delta = 15*112 = 1680
    const float* p = part + ((size_t)(b * 96 + rlo) * 16 + (i - rlo + 7)) * 112 + j;
    f32x4 s = {0.f, 0.f, 0.f, 0.f};
    for (int r = rlo; r <= rhi; ++r) {
        s += *(const f32x4*)p;
        p += 1680;
    }
    float* ob = out + (size_t)b * 9409 + i * 97 + j;
    ob[0] = s[0] * OUT_SCALE;
    if (j < 96) {
        ob[1] = s[1] * OUT_SCALE;
        ob[2] = s[2] * OUT_SCALE;
        ob[3] = s[3] * OUT_SCALE;
    }
}

// ---------------------------------------------------------------------------
extern "C" void kernel_launch(void* const* d_in, const int* in_sizes, int n_in,
                              void* d_out, int out_size, void* d_ws, size_t ws_size,
                              hipStream_t stream)
{
    const float* z  = (const float*)d_in[0];
    const float* x  = (const float*)d_in[1];
    const float* wz = (const float*)d_in[2];
    const float* bz = (const float*)d_in[3];
    const float* wx = (const float*)d_in[4];
    const float* bx = (const float*)d_in[5];
    float* out = (float*)d_out;

    // workspace: ZB (2 MB) then part[64][96][16][112] f32 (44.04 MB)
    ushortT* zbuf = (ushortT*)d_ws;
    float*   partw = (float*)((char*)d_ws + (size_t)64 * 16384 * 2);

    k_gelu_z<<<dim3(64, 4), 256, 0, stream>>>(z, wz, bz, zbuf);
    k_fused<<<dim3(3072), 512, 0, stream>>>(x, wx, bx, zbuf, partw);
    const int nred = 64 * 97 * 25;
    k_reduce<<<dim3((nred + 255) / 256), 256, 0, stream>>>(partw, out);

    (void)in_sizes; (void)n_in; (void)ws_size; (void)out_size;
}

// Round 6
// 321.734 us; speedup vs baseline: 1.2545x; 1.0092x over previous
//
#include <hip/hip_runtime.h>
#include <hip/hip_bf16.h>

typedef unsigned short ushortT;
typedef __bf16 bf16x8 __attribute__((ext_vector_type(8)));
typedef float f32x4 __attribute__((ext_vector_type(4)));

#define OUT_SCALE 0.001f

// fast GELU: v * sigmoid(1.5957691*(v + 0.044715 v^3)); |err vs exact| <~1e-3
__device__ __forceinline__ float gelu_fast(float v) {
    const float u = v * fmaf(0.044715f * v, v, 1.0f);
    const float e = __expf(-1.5957691216057308f * u);
    return v * __builtin_amdgcn_rcpf(1.0f + e);
}
__device__ __forceinline__ ushortT f2bf(float f) {
    __hip_bfloat16 h = __float2bfloat16(f);
    return *reinterpret_cast<ushortT*>(&h);
}

// ---------------------------------------------------------------------------
// K2: z path, split per 16 channels. grid (64,4), 256 thr, LDS 16.6 KB.
// gelu(z + dwconv3x3(z) + b) -> bf16 ZB[b][v][u][c64]
// ---------------------------------------------------------------------------
__global__ __launch_bounds__(256) void k_gelu_z(
    const float* __restrict__ z, const float* __restrict__ wz,
    const float* __restrict__ bz, ushortT* __restrict__ zbuf)
{
    const int b  = blockIdx.x;
    const int cg = blockIdx.y;        // channel group of 16
    const int tid = threadIdx.x;

    __shared__ float zs[16 * 260];    // 16 ch x 256 (+4 pad)

    for (int i = tid; i < 1024; i += 256) {
        const int c_l = i >> 6, pos = i & 63;
        *(float4*)(zs + c_l * 260 + pos * 4) =
            *(const float4*)(z + ((size_t)(b * 64 + cg * 16 + c_l)) * 256 + pos * 4);
    }
    __syncthreads();

    const int c_l = tid & 15;         // local channel
    const int v   = tid >> 4;         // search col (0..15)
    const int c   = cg * 16 + c_l;

    float w[9];
    #pragma unroll
    for (int i = 0; i < 9; ++i) w[i] = wz[c * 9 + i];
    const float bias = bz[c];
    const float* zc = zs + c_l * 260;
    ushortT* zo = zbuf + (size_t)b * 16384 + c;

    #pragma unroll
    for (int u = 0; u < 16; ++u) {
        float acc = bias;
        #pragma unroll
        for (int dr = 0; dr < 3; ++dr) {
            const int uu = u + dr - 1;
            if (uu < 0 || uu >= 16) continue;
            #pragma unroll
            for (int dc = 0; dc < 3; ++dc) {
                const int vv = v + dc - 1;
                if (vv < 0 || vv >= 16) continue;
                acc += zc[uu * 16 + vv] * w[dr * 3 + dc];
            }
        }
        const float y = acc + zc[u * 16 + v];
        zo[(v * 16 + u) * 64] = f2bf(gelu_fast(y));
    }
}

// ---------------------------------------------------------------------------
// K-fused (R=2): gelu-x + correlation, ONE barrier, ILP-forced schedule.
// Phase A: 15 float4 loads staged up-front in registers (rows r0-1..r0+1),
// s=3 row's 5 loads issued under the s=0 FMA block; block-uniform row-OOB
// branches; whole-vector col-edge zeroing.
// Phase B: software-pipelined ds_read (v+1 prefetch) -> 2 MFMA per v;
// f32x4 stores straight to part[b][r][ii][112] (disjoint, no atomics).
// ---------------------------------------------------------------------------
__global__ __launch_bounds__(512, 4) void k_fused(
    const float* __restrict__ x, const float* __restrict__ wx,
    const float* __restrict__ bx, const ushortT* __restrict__ zbuf,
    float* __restrict__ part)
{
    // bijective XCD swizzle: 3072 = 8 * 384; XCD i gets b in [8i, 8i+8)
    const int lin = blockIdx.x;
    const int sw  = ((lin & 7) * 384) + (lin >> 3);
    const int k2  = sw % 48;
    const int b   = sw / 48;
    const int r0  = k2 * 2;
    const int tid = threadIdx.x;

    __shared__ ushortT rowbuf[2][8192];   // per row: [g2][T128][c32 swizzled]

    const int c = tid >> 3, colg = tid & 7, j0 = colg * 12;
    const int g_ = c >> 5, cl = c & 31, chunk = cl >> 3, pos = cl & 7;
    const float* xb = x + (size_t)(b * 64 + c) * 9216;

    // ---- Phase A: stage loads FIRST (maximize loads in flight) ----
    float4 LvA[15];   // rows r0-1, r0, r0+1 (s = 0,1,2)
    {
        #pragma unroll
        for (int s = 0; s < 3; ++s) {
            const int rr  = r0 - 1 + s;
            const int rcl = (rr < 0) ? 0 : rr;      // only s=0 can underflow
            const float* xr = xb + rcl * 96;
            #pragma unroll
            for (int m = 0; m < 5; ++m) {
                const int cs  = j0 - 4 + 4 * m;
                const int csc = (cs < 0) ? 0 : (cs > 92 ? 92 : cs);
                LvA[s * 5 + m] = *(const float4*)(xr + csc);
            }
        }
    }

    // zero-pad T in [0,8) and [104,128) for rows x g: 512 uint4, one/thread
    {
        const int row = tid >> 8, g = (tid >> 7) & 1, t = tid & 127;
        const int off = (t < 32) ? t * 8 : 3328 + (t - 32) * 8;
        *(uint4*)(&rowbuf[row][g * 4096 + off]) = make_uint4(0, 0, 0, 0);
    }

    float w[9];
    #pragma unroll
    for (int i = 0; i < 9; ++i) w[i] = wx[c * 9 + i];
    const float bias = bx[c];

    const bool ledge = (colg == 0), redge = (colg == 7);
    const float4 z4 = make_float4(0.f, 0.f, 0.f, 0.f);
    #pragma unroll
    for (int s = 0; s < 3; ++s) {
        if (ledge) LvA[s * 5 + 0] = z4;
        if (redge) LvA[s * 5 + 4] = z4;
    }

    float acc0[12], acc1[12];
    #pragma unroll
    for (int jj = 0; jj < 12; ++jj) { acc0[jj] = bias; acc1[jj] = bias; }

    // s=0 (row r0-1) -> acc0 w[0..2]; block-uniform skip at r0==0
    if (r0 > 0) {
        float f[20];
        #pragma unroll
        for (int m = 0; m < 5; ++m) {
            f[4*m+0] = LvA[m].x; f[4*m+1] = LvA[m].y;
            f[4*m+2] = LvA[m].z; f[4*m+3] = LvA[m].w;
        }
        #pragma unroll
        for (int jj = 0; jj < 12; ++jj)
            acc0[jj] += f[jj+3]*w[0] + f[jj+4]*w[1] + f[jj+5]*w[2];
    }

    // issue s=3 row loads now (latency hidden under s=1/s=2 FMA blocks)
    float4 LvB[5];
    {
        const int rr  = r0 + 2;
        const int rcl = (rr > 95) ? 95 : rr;
        const float* xr = xb + rcl * 96;
        #pragma unroll
        for (int m = 0; m < 5; ++m) {
            const int cs  = j0 - 4 + 4 * m;
            const int csc = (cs < 0) ? 0 : (cs > 92 ? 92 : cs);
            LvB[m] = *(const float4*)(xr + csc);
        }
    }

    // s=1 (row r0): acc0 w[3..5] + residual; acc1 w[0..2]
    {
        float f[20];
        #pragma unroll
        for (int m = 0; m < 5; ++m) {
            f[4*m+0] = LvA[5+m].x; f[4*m+1] = LvA[5+m].y;
            f[4*m+2] = LvA[5+m].z; f[4*m+3] = LvA[5+m].w;
        }
        #pragma unroll
        for (int jj = 0; jj < 12; ++jj) {
            acc0[jj] += f[jj+3]*w[3] + f[jj+4]*w[4] + f[jj+5]*w[5] + f[jj+4];
            acc1[jj] += f[jj+3]*w[0] + f[jj+4]*w[1] + f[jj+5]*w[2];
        }
    }

    // s=2 (row r0+1): acc0 w[6..8]; acc1 w[3..5] + residual
    {
        float f[20];
        #pragma unroll
        for (int m = 0; m < 5; ++m) {
            f[4*m+0] = LvA[10+m].x; f[4*m+1] = LvA[10+m].y;
            f[4*m+2] = LvA[10+m].z; f[4*m+3] = LvA[10+m].w;
        }
        #pragma unroll
        for (int jj = 0; jj < 12; ++jj) {
            acc0[jj] += f[jj+3]*w[6] + f[jj+4]*w[7] + f[jj+5]*w[8];
            acc1[jj] += f[jj+3]*w[3] + f[jj+4]*w[4] + f[jj+5]*w[5] + f[jj+4];
        }
    }

    // s=3 (row r0+2) -> acc1 w[6..8]; block-uniform skip at r0==94
    if (r0 < 94) {
        float f[20];
        if (ledge) LvB[0] = z4;
        if (redge) LvB[4] = z4;
        #pragma unroll
        for (int m = 0; m < 5; ++m) {
            f[4*m+0] = LvB[m].x; f[4*m+1] = LvB[m].y;
            f[4*m+2] = LvB[m].z; f[4*m+3] = LvB[m].w;
        }
        #pragma unroll
        for (int jj = 0; jj < 12; ++jj)
            acc1[jj] += f[jj+3]*w[6] + f[jj+4]*w[7] + f[jj+5]*w[8];
    }

    // gelu + bf16 pack + swizzled LDS transpose write
    {
        ushortT* rbw0 = &rowbuf[0][0] + g_ * 4096;
        ushortT* rbw1 = &rowbuf[1][0] + g_ * 4096;
        #pragma unroll
        for (int jj = 0; jj < 12; ++jj) {
            const int T  = j0 + jj + 8;
            const int sh = T * 32 + ((chunk ^ ((T >> 1) & 3)) << 3) + pos;
            rbw0[sh] = f2bf(gelu_fast(acc0[jj]));
            rbw1[sh] = f2bf(gelu_fast(acc1[jj]));
        }
    }
    __syncthreads();

    // ---- Phase B: MFMA, waves 0..6 own j-tile j0a = 16*wave ----
    const int wave = tid >> 6;
    const int lane = tid & 63;
    const int n    = lane & 15;   // u (B col) == A row within tile
    const int q    = lane >> 4;   // k-chunk / C row-group
    if (wave < 7) {
        const int j0a = wave * 16;
        const ushortT* zb = zbuf + (size_t)b * 16384;
        f32x4 acc0 = {0.f, 0.f, 0.f, 0.f};
        f32x4 acc1 = {0.f, 0.f, 0.f, 0.f};

        #pragma unroll
        for (int g = 0; g < 2; ++g) {
            bf16x8 bfrag[16];
            #pragma unroll
            for (int v = 0; v < 16; ++v)
                bfrag[v] = *(const bf16x8*)(zb + (v * 16 + n) * 64 + g * 32 + 8 * q);

            // software-pipelined: prefetch v+1 A-frags during v's MFMAs
            int T0 = j0a + n;
            int o0 = (g * 128 + T0) * 32 + ((q ^ ((T0 >> 1) & 3)) << 3);
            bf16x8 a0c = *(const bf16x8*)(&rowbuf[0][0] + o0);
            bf16x8 a1c = *(const bf16x8*)(&rowbuf[1][0] + o0);
            #pragma unroll
            for (int v = 0; v < 16; ++v) {
                bf16x8 a0n, a1n;
                if (v < 15) {
                    const int T2 = j0a + n + v + 1;
                    const int o2 = (g * 128 + T2) * 32 + ((q ^ ((T2 >> 1) & 3)) << 3);
                    a0n = *(const bf16x8*)(&rowbuf[0][0] + o2);
                    a1n = *(const bf16x8*)(&rowbuf[1][0] + o2);
                }
                acc0 = __builtin_amdgcn_mfma_f32_16x16x32_bf16(a0c, bfrag[v], acc0, 0, 0, 0);
                acc1 = __builtin_amdgcn_mfma_f32_16x16x32_bf16(a1c, bfrag[v], acc1, 0, 0, 0);
                if (v < 15) { a0c = a0n; a1c = a1n; }
            }
        }

        // direct stores: part[b][r][ii=15-n][j0a+4q .. +3], disjoint per lane
        const int ii = 15 - n;
        const int joff = j0a + 4 * q;
        f32x4* p0 = (f32x4*)(part + ((size_t)(b * 96 + r0) * 16 + ii) * 112 + joff);
        *p0 = acc0;
        f32x4* p1 = (f32x4*)(part + ((size_t)(b * 96 + r0 + 1) * 16 + ii) * 112 + joff);
        *p1 = acc1;
    }
}

// ---------------------------------------------------------------------------
// K-reduce (vectorized): out[b][i][4j4..] = OUT_SCALE * sum_r part band rows.
// Each thread: 4 consecutive j via f32x4 band loads (<=16 terms).
// ---------------------------------------------------------------------------
__global__ __launch_bounds__(256) void k_reduce(
    const float* __restrict__ part, float* __restrict__ out)
{
    const int gid = blockIdx.x * 256 + threadIdx.x;
    if (gid >= 64 * 97 * 25) return;
    const int j4 = gid % 25;
    const int t  = gid / 25;
    const int i  = t % 97;
    const int b  = t / 97;
    const int j  = j4 * 4;

    int rlo = i - 8;  if (rlo < 0)  rlo = 0;
    int rhi = i + 7;  if (rhi > 95) rhi = 95;

    // index ((b*96 + r)*16 + (i-r+7))*112 + j ; per r++ delta = 15*112 = 1680
    const float* p = part + ((size_t)(b * 96 + rlo) * 16 + (i - rlo + 7)) * 112 + j;
    f32x4 s = {0.f, 0.f, 0.f, 0.f};
    for (int r = rlo; r <= rhi; ++r) {
        s += *(const f32x4*)p;
        p += 1680;
    }
    float* ob = out + (size_t)b * 9409 + i * 97 + j;
    ob[0] = s[0] * OUT_SCALE;
    if (j < 96) {
        ob[1] = s[1] * OUT_SCALE;
        ob[2] = s[2] * OUT_SCALE;
        ob[3] = s[3] * OUT_SCALE;
    }
}

// ---------------------------------------------------------------------------
extern "C" void kernel_launch(void* const* d_in, const int* in_sizes, int n_in,
                              void* d_out, int out_size, void* d_ws, size_t ws_size,
                              hipStream_t stream)
{
    const float* z  = (const float*)d_in[0];
    const float* x  = (const float*)d_in[1];
    const float* wz = (const float*)d_in[2];
    const float* bz = (const float*)d_in[3];
    const float* wx = (const float*)d_in[4];
    const float* bx = (const float*)d_in[5];
    float* out = (float*)d_out;

    // workspace: ZB (2 MB) then part[64][96][16][112] f32 (44.04 MB)
    ushortT* zbuf = (ushortT*)d_ws;
    float*   partw = (float*)((char*)d_ws + (size_t)64 * 16384 * 2);

    k_gelu_z<<<dim3(64, 4), 256, 0, stream>>>(z, wz, bz, zbuf);
    k_fused<<<dim3(3072), 512, 0, stream>>>(x, wx, bx, zbuf, partw);
    const int nred = 64 * 97 * 25;
    k_reduce<<<dim3((nred + 255) / 256), 256, 0, stream>>>(partw, out);

    (void)in_sizes; (void)n_in; (void)ws_size; (void)out_size;
}